// Round 1
// baseline (2012.198 us; speedup 1.0000x reference)
//
#include <hip/hip_runtime.h>
#include <math.h>

// Viterbi posterior_mode, bitwise-faithful to the f32 reference:
//   alpha_{t}[j] = max_i(alpha_{t-1}[i] + LT[i][j]) + e_t   (f32, RTNE, first-win argmax)
// Two-phase: K1 sequential alpha-only (boundary snapshots), K2 parallel per-chunk
// recompute with backpointers + fused map composition, K3/K4 backtrack.

#define BB 256
#define TT 8192
#define SS 32
#define LCH 256
#define NCH 32

static constexpr size_t OFF_LTC  = 0;                                    // 32*32 f32 col-major
static constexpr size_t OFF_LI   = 4096;                                 // 32 f32
static constexpr size_t OFF_BND  = 8192;                                 // NCH*BB*SS f32
static constexpr size_t OFF_LAST = OFF_BND + (size_t)NCH * BB * SS * 4;  // BB i32
static constexpr size_t OFF_H    = OFF_LAST + (size_t)BB * 4;            // NCH*BB*SS u8
static constexpr size_t OFF_SE   = OFF_H + (size_t)NCH * BB * SS;        // NCH*BB u8
static constexpr size_t OFF_BP   = (OFF_SE + (size_t)NCH * BB + 4095) & ~(size_t)4095; // TT*BB*SS u8

static __device__ __forceinline__ float rlane(float v, int i) {
  return __int_as_float(__builtin_amdgcn_readlane(__float_as_int(v), i));
}
// e = (-0.5 * x) * x - HALF_LOG_2PI, exactly as the reference (no FMA contraction)
static __device__ __forceinline__ float emis_f(float x) {
  return __fsub_rn(__fmul_rn(__fmul_rn(-0.5f, x), x), 0.9189385332046727f);
}

// ---- K0: logs (double route -> correctly rounded f32) ----
__global__ void k_prep(const float* __restrict__ hmm, float* __restrict__ ltc,
                       float* __restrict__ li) {
  int tid = threadIdx.x;
  for (int k = tid; k < SS * SS; k += 256) {
    int i = k >> 5, j = k & 31;
    ltc[j * SS + i] = (float)log((double)hmm[i * SS + j]);  // column-major for lane j
  }
  if (tid < SS) li[tid] = (float)log((double)hmm[tid]);
}

// ---- K1: sequential forward, alpha only ----
static __device__ __forceinline__ float vstep(float a, const float* lt, float e) {
  float c[32];
#pragma unroll
  for (int i = 0; i < 32; ++i) c[i] = __fadd_rn(rlane(a, i), lt[i]);
#pragma unroll
  for (int st = 16; st >= 1; st >>= 1) {
#pragma unroll
    for (int i = 0; i < st; ++i) c[i] = fmaxf(c[i], c[i + st]);
  }
  return __fadd_rn(c[0], e);
}

__global__ __launch_bounds__(64) void k_fwd(const float* __restrict__ x,
                                            const float* __restrict__ ltc,
                                            const float* __restrict__ li,
                                            float* __restrict__ bnd,
                                            int* __restrict__ last) {
  const int b = blockIdx.x, tid = threadIdx.x, j = tid & 31;
  const float* xb = x + (size_t)b * TT;
  float lt[32];
#pragma unroll
  for (int i = 0; i < 32; ++i) lt[i] = ltc[j * SS + i];

  float xv = xb[tid];
  float ev = emis_f(xv);
  float alpha = __fadd_rn(li[j], rlane(ev, 0));           // alpha_0
  if (tid < 32) bnd[(size_t)b * SS + j] = alpha;          // chunk 0 boundary

  for (int k = 1; k < 64; ++k) alpha = vstep(alpha, lt, rlane(ev, k));  // t=1..63

  for (int t0 = 64; t0 < TT; t0 += 64) {
    xv = xb[t0 + tid];
    ev = emis_f(xv);
    alpha = vstep(alpha, lt, rlane(ev, 0));               // t = t0
    if ((t0 & 255) == 0 && tid < 32)
      bnd[((size_t)(t0 >> 8) * BB + b) * SS + j] = alpha; // boundary alpha_{256c}
    for (int k = 1; k < 64; ++k) alpha = vstep(alpha, lt, rlane(ev, k));
  }
  // last[b] = argmax_j alpha (first max wins -> lowest lane)
  float m = alpha;
#pragma unroll
  for (int o = 16; o; o >>= 1) m = fmaxf(m, __shfl_xor(m, o, 32));
  unsigned long long msk = __ballot(alpha == m) & 0xffffffffull;
  if (tid == 0) last[b] = __ffsll(msk) - 1;
}

// ---- K2: parallel chunk recompute: backpointers + fused map composition ----
__global__ __launch_bounds__(256) void k_chunks(const float* __restrict__ x,
                                                const float* __restrict__ ltc,
                                                const float* __restrict__ bnd,
                                                unsigned char* __restrict__ bp,
                                                unsigned char* __restrict__ H) {
  __shared__ float alf[8][32];
  __shared__ float els[8][32];
  const int tid = threadIdx.x;
  const int w = tid >> 5, j = tid & 31;
  const int c = blockIdx.x >> 5;
  const int b = ((blockIdx.x & 31) << 3) + w;
  const int tlo = c * LCH;
  const int thi = (tlo + LCH < TT - 1) ? (tlo + LCH) : (TT - 1);
  float lt[32];
  {
    const float4* ltv = (const float4*)(ltc + (size_t)j * SS);
#pragma unroll
    for (int q = 0; q < 8; ++q) {
      float4 v = ltv[q];
      lt[4 * q + 0] = v.x; lt[4 * q + 1] = v.y; lt[4 * q + 2] = v.z; lt[4 * q + 3] = v.w;
    }
  }
  float alpha = bnd[((size_t)c * BB + b) * SS + j];
  int comp = j;  // composed map: end-state -> state at tlo
  const float* xb = x + (size_t)b * TT;

  for (int tg = tlo + 1; tg <= thi; tg += 32) {
    const int kn = (32 < thi - tg + 1) ? 32 : (thi - tg + 1);
    float xv = (j < kn) ? xb[tg + j] : 0.0f;
    els[w][j] = emis_f(xv);   // half-wave private, lockstep -> no barrier
    for (int k = 0; k < kn; ++k) {
      const int t = tg + k;
      alf[w][j] = alpha;
      float sc[32];
      const float4* ap = (const float4*)alf[w];
#pragma unroll
      for (int q = 0; q < 8; ++q) {
        float4 v = ap[q];
        sc[4 * q + 0] = __fadd_rn(v.x, lt[4 * q + 0]);
        sc[4 * q + 1] = __fadd_rn(v.y, lt[4 * q + 1]);
        sc[4 * q + 2] = __fadd_rn(v.z, lt[4 * q + 2]);
        sc[4 * q + 3] = __fadd_rn(v.w, lt[4 * q + 3]);
      }
      // max value (order-free, exact), then first-win index via descending eq-scan
      float m = sc[0];
#pragma unroll
      for (int i = 1; i < 32; ++i) m = fmaxf(m, sc[i]);
      int idx = 31;
#pragma unroll
      for (int i = 30; i >= 0; --i) idx = (sc[i] == m) ? i : idx;
      alpha = __fadd_rn(m, els[w][k]);
      bp[(size_t)t * (BB * SS) + (size_t)b * SS + j] = (unsigned char)idx;
      comp = __shfl(comp, idx, 32);  // comp_new[j] = comp_old[bp_t[j]]
    }
  }
  H[((size_t)c * BB + b) * SS + j] = (unsigned char)comp;
}

// ---- K3: boundary backtrack over composed chunk maps (+ states[b][0]) ----
__global__ void k_bound(const int* __restrict__ last, const unsigned char* __restrict__ H,
                        unsigned char* __restrict__ se, int* __restrict__ out) {
  int b = threadIdx.x;  // one block of 256
  int s = last[b];
  for (int c = NCH - 1; c >= 0; --c) {
    se[(size_t)c * BB + b] = (unsigned char)s;      // state at t_hi(c)
    s = H[((size_t)c * BB + b) * SS + s];           // -> state at 256c
  }
  out[(size_t)b * TT] = s;                          // states[b][0]
}

// ---- K4: fill per-chunk paths from bp (LDS-staged walk) ----
__global__ __launch_bounds__(256) void k_fill(const unsigned char* __restrict__ bp,
                                              const unsigned char* __restrict__ se,
                                              int* __restrict__ out) {
  __shared__ unsigned char lbp[8][LCH * SS];  // 64 KiB
  const int tid = threadIdx.x;
  const int w = tid >> 5, j = tid & 31;
  const int c = blockIdx.x >> 5;
  const int b = ((blockIdx.x & 31) << 3) + w;
  const int tlo = c * LCH;
  const int thi = (tlo + LCH < TT - 1) ? (tlo + LCH) : (TT - 1);
  const int n = thi - tlo;
  for (int k = 0; k < n; ++k)
    lbp[w][k * SS + j] = bp[(size_t)(tlo + 1 + k) * (BB * SS) + (size_t)b * SS + j];
  __builtin_amdgcn_wave_barrier();
  if (j == 0) {
    int s = se[(size_t)c * BB + b];                 // state at t_hi
    int* ob = out + (size_t)b * TT;
    for (int k = n - 1; k >= 0; --k) {
      ob[tlo + 1 + k] = s;
      s = lbp[w][k * SS + s];
    }
  }
}

extern "C" void kernel_launch(void* const* d_in, const int* in_sizes, int n_in,
                              void* d_out, int out_size, void* d_ws, size_t ws_size,
                              hipStream_t stream) {
  const float* x   = (const float*)d_in[0];   // inputs [B,T] f32
  const float* hmm = (const float*)d_in[1];   // hmm_params [U,S,S] f32 (only [0] used)
  int* out = (int*)d_out;                     // states [B,T] int32
  char* ws = (char*)d_ws;

  float* ltc = (float*)(ws + OFF_LTC);
  float* li  = (float*)(ws + OFF_LI);
  float* bnd = (float*)(ws + OFF_BND);
  int*   lst = (int*)(ws + OFF_LAST);
  unsigned char* H  = (unsigned char*)(ws + OFF_H);
  unsigned char* se = (unsigned char*)(ws + OFF_SE);
  unsigned char* bp = (unsigned char*)(ws + OFF_BP);

  k_prep  <<<1,    256, 0, stream>>>(hmm, ltc, li);
  k_fwd   <<<BB,   64,  0, stream>>>(x, ltc, li, bnd, lst);
  k_chunks<<<1024, 256, 0, stream>>>(x, ltc, bnd, bp, H);
  k_bound <<<1,    256, 0, stream>>>(lst, H, se, out);
  k_fill  <<<1024, 256, 0, stream>>>(bp, se, out);
}

// Round 3
// 1493.076 us; speedup vs baseline: 1.3477x; 1.3477x over previous
//
#include <hip/hip_runtime.h>
#include <math.h>

// Viterbi posterior_mode, bitwise-faithful to the f32 reference:
//   alpha_{t}[j] = max_i(alpha_{t-1}[i] + LT[i][j]) + e_t   (f32, RTNE, first-win argmax)
// K1 sequential alpha-only (xor-butterfly matvec, half-split across lane halves),
// K2 parallel per-chunk recompute with backpointers + fused map composition, K3/K4 backtrack.

#define BB 256
#define TT 8192
#define SS 32
#define LCH 256
#define NCH 32

static constexpr size_t OFF_LTC  = 0;                                    // 32*32 f32 col-major
static constexpr size_t OFF_LI   = 4096;                                 // 32 f32
static constexpr size_t OFF_BND  = 8192;                                 // NCH*BB*SS f32
static constexpr size_t OFF_LAST = OFF_BND + (size_t)NCH * BB * SS * 4;  // BB i32
static constexpr size_t OFF_H    = OFF_LAST + (size_t)BB * 4;            // NCH*BB*SS u8
static constexpr size_t OFF_SE   = OFF_H + (size_t)NCH * BB * SS;        // NCH*BB u8
static constexpr size_t OFF_BP   = (OFF_SE + (size_t)NCH * BB + 4095) & ~(size_t)4095; // TT*BB*SS u8

static __device__ __forceinline__ float rlane(float v, int i) {
  return __int_as_float(__builtin_amdgcn_readlane(__float_as_int(v), i));
}
// e = (-0.5 * x) * x - HALF_LOG_2PI, exactly as the reference (no FMA contraction)
static __device__ __forceinline__ float emis_f(float x) {
  return __fsub_rn(__fmul_rn(__fmul_rn(-0.5f, x), x), 0.9189385332046727f);
}

// lane-swizzle within 32-lane groups: lane <- lane ^ R  (bit mode, and=0x1F)
template<int R>
static __device__ __forceinline__ float swz(float v) {
  return __int_as_float(__builtin_amdgcn_ds_swizzle(__float_as_int(v), (R << 10) | 0x1F));
}

// ---- K0: logs (double route -> correctly rounded f32) ----
__global__ void k_prep(const float* __restrict__ hmm, float* __restrict__ ltc,
                       float* __restrict__ li) {
  int tid = threadIdx.x;
  for (int k = tid; k < SS * SS; k += 256) {
    int i = k >> 5, j = k & 31;
    ltc[j * SS + i] = (float)log((double)hmm[i * SS + j]);  // column-major for column j
  }
  if (tid < SS) li[tid] = (float)log((double)hmm[tid]);
}

// ---- K1 step: (max,+) matvec, 16 candidates per lane, xor delivery ----
// Layouts: "plain"  : lane l holds alpha_{l&31} (both halves)
//          "shifted": lane l<32 holds alpha_l, lane l>=32 holds alpha_{(l&31)^16}
// ODD_T (variant A): consumes plain, produces shifted; combine = shfl_xor 48, consts ltA.
// !ODD_T (variant B): consumes shifted, produces plain; combine = shfl_xor 32, consts ltB.
template<bool ODD_T>
static __device__ __forceinline__ float fstep(float a, const float* ltA, const float* ltB,
                                              float e) {
  const float* lt = ODD_T ? ltA : ltB;
  float c[16];
  c[0] = __fadd_rn(a, lt[0]);
#define CAND(r) c[r] = __fadd_rn(swz<r>(a), lt[r]);
  CAND(1) CAND(2) CAND(3) CAND(4) CAND(5) CAND(6) CAND(7) CAND(8)
  CAND(9) CAND(10) CAND(11) CAND(12) CAND(13) CAND(14) CAND(15)
#undef CAND
#pragma unroll
  for (int s = 8; s >= 1; s >>= 1) {
#pragma unroll
    for (int i = 0; i < s; ++i) c[i] = fmaxf(c[i], c[i + s]);
  }
  float q = __shfl_xor(c[0], ODD_T ? 48 : 32, 64);
  float pm = fmaxf(c[0], q);
  return __fadd_rn(pm, e);
}

__global__ __launch_bounds__(64) void k_fwd(const float* __restrict__ x,
                                            const float* __restrict__ ltc,
                                            const float* __restrict__ li,
                                            float* __restrict__ bnd,
                                            int* __restrict__ last) {
  const int b = blockIdx.x, tid = threadIdx.x;
  const int m = tid & 31;
  const int hi = (tid & 32) >> 1;  // 16 for upper half, 0 for lower
  // Variant A: lane computes column (m^hi) partial over i in {m^r}:   ltA[r]=lt[m^r][m^hi]
  // Variant B: lane computes column m     partial over i in {m^r^hi}: ltB[r]=lt[m^r^hi][m]
  float ltA[16], ltB[16];
#pragma unroll
  for (int r = 0; r < 16; ++r) {
    ltA[r] = ltc[(size_t)(m ^ hi) * SS + (m ^ r)];
    ltB[r] = ltc[(size_t)m * SS + (m ^ r ^ hi)];
  }
  const float* xb = x + (size_t)b * TT;
  float xv = xb[m];                       // t = 0..31 (both halves read same 32)
  float ev = emis_f(xv);
  float a = __fadd_rn(li[m], rlane(ev, 0));  // alpha_0, plain layout
  if (tid < 32) bnd[(size_t)b * SS + m] = a; // chunk-0 boundary

  float xv2 = xb[32 + m];
#pragma unroll
  for (int k = 1; k < 32; ++k) {           // t = 1..31  (t odd -> A, even -> B)
    float e = rlane(ev, k);
    if (k & 1) a = fstep<true>(a, ltA, ltB, e);
    else       a = fstep<false>(a, ltA, ltB, e);
  }
  for (int t0 = 32; t0 < TT; t0 += 32) {
    ev = emis_f(xv2);
    float xv3 = 0.0f;
    if (t0 + 32 < TT) xv3 = xb[t0 + 32 + m];
    a = fstep<false>(a, ltA, ltB, rlane(ev, 0));  // t = t0 (even -> B, plain out)
    if ((t0 & 255) == 0 && tid < 32)
      bnd[((size_t)(t0 >> 8) * BB + b) * SS + m] = a;  // boundary alpha_{256c}
#pragma unroll
    for (int k = 1; k < 32; ++k) {
      float e = rlane(ev, k);
      if (k & 1) a = fstep<true>(a, ltA, ltB, e);
      else       a = fstep<false>(a, ltA, ltB, e);
    }
    xv2 = xv3;
  }
  // last[b] = argmax_j alpha (first max wins). Lower 32 lanes hold plain alpha.
  float mr = a;
#pragma unroll
  for (int o = 16; o; o >>= 1) mr = fmaxf(mr, __shfl_xor(mr, o, 32));
  unsigned long long msk = __ballot(a == mr) & 0xffffffffull;
  if (tid == 0) last[b] = __ffsll(msk) - 1;
}

// ---- K2: parallel chunk recompute: backpointers + fused map composition ----
__global__ __launch_bounds__(256) void k_chunks(const float* __restrict__ x,
                                                const float* __restrict__ ltc,
                                                const float* __restrict__ bnd,
                                                unsigned char* __restrict__ bp,
                                                unsigned char* __restrict__ H) {
  __shared__ float alf[8][32];
  __shared__ float els[8][32];
  const int tid = threadIdx.x;
  const int w = tid >> 5, j = tid & 31;
  const int c = blockIdx.x >> 5;
  const int b = ((blockIdx.x & 31) << 3) + w;
  const int tlo = c * LCH;
  const int thi = (tlo + LCH < TT - 1) ? (tlo + LCH) : (TT - 1);
  float lt[32];
  {
    const float4* ltv = (const float4*)(ltc + (size_t)j * SS);
#pragma unroll
    for (int q = 0; q < 8; ++q) {
      float4 v = ltv[q];
      lt[4 * q + 0] = v.x; lt[4 * q + 1] = v.y; lt[4 * q + 2] = v.z; lt[4 * q + 3] = v.w;
    }
  }
  float alpha = bnd[((size_t)c * BB + b) * SS + j];
  int comp = j;  // composed map: end-state -> state at tlo
  const float* xb = x + (size_t)b * TT;

  for (int tg = tlo + 1; tg <= thi; tg += 32) {
    const int kn = (32 < thi - tg + 1) ? 32 : (thi - tg + 1);
    float xv = (j < kn) ? xb[tg + j] : 0.0f;
    els[w][j] = emis_f(xv);   // half-wave private, lockstep -> no barrier
    for (int k = 0; k < kn; ++k) {
      const int t = tg + k;
      alf[w][j] = alpha;
      float sc[32];
      const float4* ap = (const float4*)alf[w];
#pragma unroll
      for (int q = 0; q < 8; ++q) {
        float4 v = ap[q];
        sc[4 * q + 0] = __fadd_rn(v.x, lt[4 * q + 0]);
        sc[4 * q + 1] = __fadd_rn(v.y, lt[4 * q + 1]);
        sc[4 * q + 2] = __fadd_rn(v.z, lt[4 * q + 2]);
        sc[4 * q + 3] = __fadd_rn(v.w, lt[4 * q + 3]);
      }
      // max value (order-free, exact), then first-win index via descending eq-scan
      float m = sc[0];
#pragma unroll
      for (int i = 1; i < 32; ++i) m = fmaxf(m, sc[i]);
      int idx = 31;
#pragma unroll
      for (int i = 30; i >= 0; --i) idx = (sc[i] == m) ? i : idx;
      alpha = __fadd_rn(m, els[w][k]);
      bp[(size_t)t * (BB * SS) + (size_t)b * SS + j] = (unsigned char)idx;
      comp = __shfl(comp, idx, 32);  // comp_new[j] = comp_old[bp_t[j]]
    }
  }
  H[((size_t)c * BB + b) * SS + j] = (unsigned char)comp;
}

// ---- K3: boundary backtrack over composed chunk maps (+ states[b][0]) ----
__global__ void k_bound(const int* __restrict__ last, const unsigned char* __restrict__ H,
                        unsigned char* __restrict__ se, int* __restrict__ out) {
  int b = threadIdx.x;  // one block of 256
  int s = last[b];
  for (int c = NCH - 1; c >= 0; --c) {
    se[(size_t)c * BB + b] = (unsigned char)s;      // state at t_hi(c)
    s = H[((size_t)c * BB + b) * SS + s];           // -> state at 256c
  }
  out[(size_t)b * TT] = s;                          // states[b][0]
}

// ---- K4: fill per-chunk paths from bp (LDS-staged walk) ----
__global__ __launch_bounds__(256) void k_fill(const unsigned char* __restrict__ bp,
                                              const unsigned char* __restrict__ se,
                                              int* __restrict__ out) {
  __shared__ unsigned char lbp[8][LCH * SS];  // 64 KiB
  const int tid = threadIdx.x;
  const int w = tid >> 5, j = tid & 31;
  const int c = blockIdx.x >> 5;
  const int b = ((blockIdx.x & 31) << 3) + w;
  const int tlo = c * LCH;
  const int thi = (tlo + LCH < TT - 1) ? (tlo + LCH) : (TT - 1);
  const int n = thi - tlo;
  for (int k = 0; k < n; ++k)
    lbp[w][k * SS + j] = bp[(size_t)(tlo + 1 + k) * (BB * SS) + (size_t)b * SS + j];
  __builtin_amdgcn_wave_barrier();
  if (j == 0) {
    int s = se[(size_t)c * BB + b];                 // state at t_hi
    int* ob = out + (size_t)b * TT;
    for (int k = n - 1; k >= 0; --k) {
      ob[tlo + 1 + k] = s;
      s = lbp[w][k * SS + s];
    }
  }
}

extern "C" void kernel_launch(void* const* d_in, const int* in_sizes, int n_in,
                              void* d_out, int out_size, void* d_ws, size_t ws_size,
                              hipStream_t stream) {
  const float* x   = (const float*)d_in[0];   // inputs [B,T] f32
  const float* hmm = (const float*)d_in[1];   // hmm_params [U,S,S] f32 (only [0] used)
  int* out = (int*)d_out;                     // states [B,T] int32
  char* ws = (char*)d_ws;

  float* ltc = (float*)(ws + OFF_LTC);
  float* li  = (float*)(ws + OFF_LI);
  float* bnd = (float*)(ws + OFF_BND);
  int*   lst = (int*)(ws + OFF_LAST);
  unsigned char* H  = (unsigned char*)(ws + OFF_H);
  unsigned char* se = (unsigned char*)(ws + OFF_SE);
  unsigned char* bp = (unsigned char*)(ws + OFF_BP);

  k_prep  <<<1,    256, 0, stream>>>(hmm, ltc, li);
  k_fwd   <<<BB,   64,  0, stream>>>(x, ltc, li, bnd, lst);
  k_chunks<<<1024, 256, 0, stream>>>(x, ltc, bnd, bp, H);
  k_bound <<<1,    256, 0, stream>>>(lst, H, se, out);
  k_fill  <<<1024, 256, 0, stream>>>(bp, se, out);
}